// Round 9
// baseline (2470.841 us; speedup 1.0000x reference)
//
#include <hip/hip_runtime.h>
#include <hip/hip_bf16.h>

// GPT forward: bf16-MFMA GEMMs + fp32 flash-attention tiles. fp32 output.
// Dims fixed: B=2, T=2048, E=512, H=8, DH=64, L=6, V=32000.
#define TT 2048
#define EE 512
#define BB 2
#define HH 8
#define LL 6
#define VV 32000

typedef __attribute__((ext_vector_type(4))) float f32x4;
typedef __attribute__((ext_vector_type(8))) short s16x8;

// ---------------------------------------------------------------- embedding
__global__ __launch_bounds__(256) void embed_kernel(
    const int* __restrict__ idx, const float* __restrict__ wte,
    const float* __restrict__ wpe, float* __restrict__ X) {
  int token = blockIdx.x;
  int t = token & (TT - 1);
  int id = idx[token];
  int e = threadIdx.x;
  const float* wrow = wte + (long)id * EE;
  const float* prow = wpe + (long)t * EE;
  float* xrow = X + (long)token * EE;
  xrow[e]       = wrow[e]       + prow[e];
  xrow[e + 256] = wrow[e + 256] + prow[e + 256];
}

// ---------------------------------------------------------------- layernorm
// One block per row (E=512). Writes fp32 (outF) and/or bf16 (outB).
__global__ __launch_bounds__(256) void ln_kernel(
    const float* __restrict__ in, long inStride,
    const float* __restrict__ g, const float* __restrict__ b,
    float* __restrict__ outF, __hip_bfloat16* __restrict__ outB,
    long outStride) {
  int row = blockIdx.x, tid = threadIdx.x;
  const float* x = in + (long)row * inStride;
  float v0 = x[tid], v1 = x[tid + 256];
  __shared__ float rs[256], rss[256];
  rs[tid] = v0 + v1;
  rss[tid] = v0 * v0 + v1 * v1;
  __syncthreads();
  for (int off = 128; off > 0; off >>= 1) {
    if (tid < off) { rs[tid] += rs[tid + off]; rss[tid] += rss[tid + off]; }
    __syncthreads();
  }
  float mu  = rs[0] * (1.0f / 512.0f);
  float var = rss[0] * (1.0f / 512.0f) - mu * mu;
  float rstd = rsqrtf(var + 1e-5f);
  float o0 = (v0 - mu) * rstd * g[tid]       + b[tid];
  float o1 = (v1 - mu) * rstd * g[tid + 256] + b[tid + 256];
  if (outF) {
    float* o = outF + (long)row * outStride;
    o[tid] = o0; o[tid + 256] = o1;
  }
  if (outB) {
    __hip_bfloat16* o = outB + (long)row * outStride;
    o[tid] = __float2bfloat16(o0); o[tid + 256] = __float2bfloat16(o1);
  }
}

// ------------------------------------------------- weight convert+transpose
// dst[n*K+k] = bf16(src[k*N+n]), per layer (blockIdx.z). 32x32 LDS tiles.
__global__ __launch_bounds__(256) void wconv_kernel(
    const float* __restrict__ src, __hip_bfloat16* __restrict__ dst,
    int K, int N, long sLS, long dLS) {
  __shared__ float TS[32][33];
  src += (long)blockIdx.z * sLS;
  dst += (long)blockIdx.z * dLS;
  int n0 = blockIdx.x * 32, k0 = blockIdx.y * 32;
  int c = threadIdx.x & 31, r4 = threadIdx.x >> 5;
#pragma unroll
  for (int i = 0; i < 4; ++i) {
    int r = r4 + i * 8;
    TS[c][r] = src[(long)(k0 + r) * N + n0 + c];
  }
  __syncthreads();
#pragma unroll
  for (int i = 0; i < 4; ++i) {
    int rn = r4 + i * 8;
    dst[(long)(n0 + rn) * K + k0 + c] = __float2bfloat16(TS[rn][c]);
  }
}

// ---------------------------------------------------------------- MFMA GEMM
// C[M,N] = act(A[M,K]bf16 @ Wt[N,K]bf16^T + bias (+resid)).
// 128x128 tile, BK=64, 4 waves (2x2, 64x64 each), 16x16x32 bf16 MFMA.
// LDS rows padded +8 bf16 (stride 144B) -> 2-way bank conflicts only.
__global__ __launch_bounds__(256) void mfma_gemm(
    const __hip_bfloat16* __restrict__ A, const __hip_bfloat16* __restrict__ Wt,
    const float* __restrict__ bias, const float* __restrict__ resid,
    float* __restrict__ Cf, __hip_bfloat16* __restrict__ Cb,
    int M, int N, int K, int act) {
  __shared__ unsigned short As[128][72];
  __shared__ unsigned short Bs[128][72];
  int tid = threadIdx.x;
  int w = tid >> 6, l = tid & 63;
  int wr = (w >> 1) * 64, wc = (w & 1) * 64;
  int row0 = blockIdx.y * 128, col0 = blockIdx.x * 128;
  f32x4 acc[4][4] = {};

  for (int k0 = 0; k0 < K; k0 += 64) {
#pragma unroll
    for (int p = 0; p < 4; ++p) {
      int chunk = p * 256 + tid;
      int r = chunk >> 3, c8 = (chunk & 7) * 8;
      *(uint4*)&As[r][c8] =
          *(const uint4*)&A[(long)(row0 + r) * K + k0 + c8];
      *(uint4*)&Bs[r][c8] =
          *(const uint4*)&Wt[(long)(col0 + r) * K + k0 + c8];
    }
    __syncthreads();
#pragma unroll
    for (int ks = 0; ks < 2; ++ks) {
      s16x8 af[4], bfr[4];
#pragma unroll
      for (int m = 0; m < 4; ++m)
        af[m] = *(const s16x8*)&As[wr + m * 16 + (l & 15)][ks * 32 + (l >> 4) * 8];
#pragma unroll
      for (int n = 0; n < 4; ++n)
        bfr[n] = *(const s16x8*)&Bs[wc + n * 16 + (l & 15)][ks * 32 + (l >> 4) * 8];
#pragma unroll
      for (int m = 0; m < 4; ++m)
#pragma unroll
        for (int n = 0; n < 4; ++n)
          acc[m][n] = __builtin_amdgcn_mfma_f32_16x16x32_bf16(
              af[m], bfr[n], acc[m][n], 0, 0, 0);
    }
    __syncthreads();
  }

  int lr = (l >> 4) * 4, lc = l & 15;
#pragma unroll
  for (int m = 0; m < 4; ++m) {
#pragma unroll
    for (int n = 0; n < 4; ++n) {
      int col = col0 + wc + n * 16 + lc;
      float bv = bias[col];
#pragma unroll
      for (int r = 0; r < 4; ++r) {
        int row = row0 + wr + m * 16 + lr + r;
        float v = acc[m][n][r] + bv;
        if (resid) v += resid[(long)row * N + col];
        if (act) v = 0.5f * v * (1.0f + erff(v * 0.70710678118f));
        if (Cf) Cf[(long)row * N + col] = v;
        if (Cb) Cb[(long)row * N + col] = __float2bfloat16(v);
      }
    }
  }
}

// ------------------------------------------------------- flash attention f32
// Block = (qtile of 64 rows, b*h). 256 threads, register-tiled 4x4 GEMMs.
// LDS: QT[d][q], KP (K^T[d][k], later aliased as P^T[k][q]), Vt[k][d].
// Online softmax state per q-row in LDS. Output bf16 (feeds proj GEMM).
__global__ __launch_bounds__(256) void attn_kernel(
    const float* __restrict__ qkv, __hip_bfloat16* __restrict__ Y) {
  __shared__ float QT[64][68];
  __shared__ float KP[64][68];   // K^T during scores, P^T during PV
  __shared__ float Vt[64][68];
  __shared__ float red[64][17];
  __shared__ float m_s[64], l_s[64], alpha_s[64];

  int qt = 31 - blockIdx.x;            // long tiles first
  int bh = blockIdx.y;
  int b = bh >> 3, h = bh & 7;
  int tid = threadIdx.x;
  int tx = tid & 15, ty = tid >> 4;
  int q0 = qt * 64;
  const long rowStride = 3 * EE;       // 1536
  const float* base = qkv + (long)b * TT * rowStride + h * 64;

  // stage Q transposed: QT[d][q]
  {
    int q = tid >> 2, g = tid & 3;
#pragma unroll
    for (int i = 0; i < 4; ++i) {
      int d0 = g * 4 + i * 16;
      float4 v = *(const float4*)&base[(long)(q0 + q) * rowStride + d0];
      QT[d0 + 0][q] = v.x; QT[d0 + 1][q] = v.y;
      QT[d0 + 2][q] = v.z; QT[d0 + 3][q] = v.w;
    }
  }
  if (tid < 64) { m_s[tid] = -3e38f; l_s[tid] = 0.0f; }

  float oacc[4][4] = {};
  const float scale = 0.125f;

  for (int kt = 0; kt <= qt; ++kt) {
    int k0 = kt * 64;
    __syncthreads();   // protect QT(first iter) / KP,Vt (prev iter reads)
    {
      int k = tid >> 2, g = tid & 3;
#pragma unroll
      for (int i = 0; i < 4; ++i) {
        int d0 = g * 4 + i * 16;
        float4 kv = *(const float4*)&base[(long)(k0 + k) * rowStride + EE + d0];
        KP[d0 + 0][k] = kv.x; KP[d0 + 1][k] = kv.y;
        KP[d0 + 2][k] = kv.z; KP[d0 + 3][k] = kv.w;
        *(float4*)&Vt[k][d0] =
            *(const float4*)&base[(long)(k0 + k) * rowStride + 2 * EE + d0];
      }
    }
    __syncthreads();

    // scores: S = Q K^T (64x64), thread owns rows ty*4+i, cols tx*4+j
    float sacc[4][4] = {};
    for (int d = 0; d < 64; ++d) {
      float4 qv = *(const float4*)&QT[d][ty * 4];
      float4 kv = *(const float4*)&KP[d][tx * 4];
      float qa[4] = {qv.x, qv.y, qv.z, qv.w};
      float ka[4] = {kv.x, kv.y, kv.z, kv.w};
#pragma unroll
      for (int i = 0; i < 4; ++i)
#pragma unroll
        for (int j = 0; j < 4; ++j) sacc[i][j] += qa[i] * ka[j];
    }
    float lm[4];
#pragma unroll
    for (int i = 0; i < 4; ++i) {
      lm[i] = -3e38f;
#pragma unroll
      for (int j = 0; j < 4; ++j) {
        float s = sacc[i][j] * scale;
        if (k0 + tx * 4 + j > q0 + ty * 4 + i) s = -3e38f;
        sacc[i][j] = s;
        lm[i] = fmaxf(lm[i], s);
      }
      red[ty * 4 + i][tx] = lm[i];
    }
    __syncthreads();
    if (tid < 64) {
      float mx = m_s[tid];
#pragma unroll
      for (int j = 0; j < 16; ++j) mx = fmaxf(mx, red[tid][j]);
      alpha_s[tid] = __expf(m_s[tid] - mx);
      m_s[tid] = mx;
    }
    __syncthreads();
    // P = exp(S - m), write P^T into KP (K-tile is dead now)
#pragma unroll
    for (int i = 0; i < 4; ++i) {
      int row = ty * 4 + i;
      float mrow = m_s[row];
      float ps = 0.0f;
#pragma unroll
      for (int j = 0; j < 4; ++j) {
        float p = __expf(sacc[i][j] - mrow);
        KP[tx * 4 + j][row] = p;
        ps += p;
      }
      red[row][tx] = ps;
    }
    __syncthreads();
    if (tid < 64) {
      float s = 0.0f;
#pragma unroll
      for (int j = 0; j < 16; ++j) s += red[tid][j];
      l_s[tid] = l_s[tid] * alpha_s[tid] + s;
    }
    // PV: O = O*alpha + P^T(V). thread owns rows ty*4+i (q), cols tx*4+j (d)
    float al[4];
#pragma unroll
    for (int i = 0; i < 4; ++i) al[i] = alpha_s[ty * 4 + i];
#pragma unroll
    for (int i = 0; i < 4; ++i)
#pragma unroll
      for (int j = 0; j < 4; ++j) oacc[i][j] *= al[i];
    for (int k = 0; k < 64; ++k) {
      float4 pv = *(const float4*)&KP[k][ty * 4];
      float4 vv = *(const float4*)&Vt[k][tx * 4];
      float pa[4] = {pv.x, pv.y, pv.z, pv.w};
      float va[4] = {vv.x, vv.y, vv.z, vv.w};
#pragma unroll
      for (int i = 0; i < 4; ++i)
#pragma unroll
        for (int j = 0; j < 4; ++j) oacc[i][j] += pa[i] * va[j];
    }
  }
  __syncthreads();  // l_s final values
#pragma unroll
  for (int i = 0; i < 4; ++i) {
    int q = q0 + ty * 4 + i;
    float inv = 1.0f / l_s[ty * 4 + i];
#pragma unroll
    for (int j = 0; j < 4; ++j) {
      Y[((long)(b * TT + q)) * EE + h * 64 + tx * 4 + j] =
          __float2bfloat16(oacc[i][j] * inv);
    }
  }
}

// ---------------------------------------------------------------- logits
// out[b*V+v] = dot(XF[b,:], wte[v,:]); one wave per output, fp32 store
// (reference output dtype is float32 -> d_out is float*).
__global__ __launch_bounds__(256) void logits_kernel(
    const float* __restrict__ XF, const float* __restrict__ wte,
    float* __restrict__ out) {
  int wid = (blockIdx.x * 256 + threadIdx.x) >> 6;
  int lane = threadIdx.x & 63;
  if (wid >= BB * VV) return;
  int b = wid / VV, v = wid - b * VV;
  const float* x = XF + (long)b * EE;
  const float* w = wte + (long)v * EE;
  float acc = 0.0f;
#pragma unroll
  for (int i = 0; i < 8; ++i) acc += x[lane + 64 * i] * w[lane + 64 * i];
  for (int off = 32; off > 0; off >>= 1) acc += __shfl_down(acc, off, 64);
  if (lane == 0) out[wid] = acc;
}

// ---------------------------------------------------------------- launch
extern "C" void kernel_launch(void* const* d_in, const int* in_sizes, int n_in,
                              void* d_out, int out_size, void* d_ws, size_t ws_size,
                              hipStream_t stream) {
  (void)in_sizes; (void)n_in; (void)out_size; (void)ws_size;
  const int*   idx   = (const int*)  d_in[0];
  const float* wte   = (const float*)d_in[1];
  const float* wpe   = (const float*)d_in[2];
  const float* ln1_g = (const float*)d_in[3];
  const float* ln1_b = (const float*)d_in[4];
  const float* Wqkv  = (const float*)d_in[5];
  const float* bqkv  = (const float*)d_in[6];
  const float* Wo    = (const float*)d_in[7];
  const float* bo    = (const float*)d_in[8];
  const float* ln2_g = (const float*)d_in[9];
  const float* ln2_b = (const float*)d_in[10];
  const float* Wfc   = (const float*)d_in[11];
  const float* bfc   = (const float*)d_in[12];
  const float* Wfc2  = (const float*)d_in[13];
  const float* bfc2  = (const float*)d_in[14];
  const float* lnf_g = (const float*)d_in[15];
  const float* lnf_b = (const float*)d_in[16];
  float* out = (float*)d_out;

  const long NTOK = (long)BB * TT;  // 4096
  float* X   = (float*)d_ws;                       // [4096,512] f32
  float* QKV = X + NTOK * EE;                      // [4096,1536] f32
  float* XF  = QKV + NTOK * 3 * EE;                // [2,512] f32 (pad to 1024)
  // ACTbf aliases QKV's storage: QKV dies at attn_kernel, ACT lives FC->FC2.
  __hip_bfloat16* ACTbf = (__hip_bfloat16*)QKV;    // [4096,2048] bf16 (16MB<24MB)
  __hip_bfloat16* Hbf   = (__hip_bfloat16*)(XF + 1024);
  __hip_bfloat16* Ybf   = Hbf + NTOK * EE;
  __hip_bfloat16* WqkvT = Ybf + NTOK * EE;         // [6][1536,512]
  __hip_bfloat16* WoT   = WqkvT + (long)LL * 3 * EE * EE;
  __hip_bfloat16* WfcT  = WoT   + (long)LL * EE * EE;
  __hip_bfloat16* Wfc2T = WfcT  + (long)LL * 4 * EE * EE;
  // total ws: ~74 MB

  // weights: fp32 [K,N] -> bf16 [N,K]
  wconv_kernel<<<dim3(3 * EE / 32, EE / 32, LL), 256, 0, stream>>>(
      Wqkv, WqkvT, EE, 3 * EE, (long)EE * 3 * EE, (long)3 * EE * EE);
  wconv_kernel<<<dim3(EE / 32, EE / 32, LL), 256, 0, stream>>>(
      Wo, WoT, EE, EE, (long)EE * EE, (long)EE * EE);
  wconv_kernel<<<dim3(4 * EE / 32, EE / 32, LL), 256, 0, stream>>>(
      Wfc, WfcT, EE, 4 * EE, (long)EE * 4 * EE, (long)4 * EE * EE);
  wconv_kernel<<<dim3(EE / 32, 4 * EE / 32, LL), 256, 0, stream>>>(
      Wfc2, Wfc2T, 4 * EE, EE, (long)4 * EE * EE, (long)EE * 4 * EE);

  embed_kernel<<<NTOK, 256, 0, stream>>>(idx, wte, wpe, X);

  for (int l = 0; l < LL; ++l) {
    ln_kernel<<<NTOK, 256, 0, stream>>>(X, EE, ln1_g + l * EE, ln1_b + l * EE,
                                        nullptr, Hbf, EE);
    mfma_gemm<<<dim3(3 * EE / 128, NTOK / 128), 256, 0, stream>>>(
        Hbf, WqkvT + (long)l * 3 * EE * EE, bqkv + (long)l * 3 * EE,
        nullptr, QKV, nullptr, NTOK, 3 * EE, EE, 0);
    attn_kernel<<<dim3(TT / 64, BB * HH), 256, 0, stream>>>(QKV, Ybf);
    mfma_gemm<<<dim3(EE / 128, NTOK / 128), 256, 0, stream>>>(
        Ybf, WoT + (long)l * EE * EE, bo + (long)l * EE,
        X, X, nullptr, NTOK, EE, EE, 0);
    ln_kernel<<<NTOK, 256, 0, stream>>>(X, EE, ln2_g + l * EE, ln2_b + l * EE,
                                        nullptr, Hbf, EE);
    mfma_gemm<<<dim3(4 * EE / 128, NTOK / 128), 256, 0, stream>>>(
        Hbf, WfcT + (long)l * 4 * EE * EE, bfc + (long)l * 4 * EE,
        nullptr, nullptr, ACTbf, NTOK, 4 * EE, EE, 1);
    mfma_gemm<<<dim3(EE / 128, NTOK / 128), 256, 0, stream>>>(
        ACTbf, Wfc2T + (long)l * EE * 4 * EE, bfc2 + (long)l * EE,
        X, X, nullptr, NTOK, EE, 4 * EE, 0);
  }

  ln_kernel<<<BB, 256, 0, stream>>>(X + (long)(TT - 1) * EE, (long)TT * EE,
                                    lnf_g, lnf_b, XF, nullptr, EE);
  logits_kernel<<<(BB * VV * 64 + 255) / 256, 256, 0, stream>>>(XF, wte, out);
}